// Round 4
// baseline (11200.002 us; speedup 1.0000x reference)
//
#include <hip/hip_runtime.h>

// ---------------------------------------------------------------------------
// 2-layer LSTM (B=64, T=256, D=512, H1=H2=1024) + dense head.
// R4: persistent cooperative kernel + hand-pipelined A-loads.
// R3 post-mortem: MfmaUtil 1.7%/VGPR 32 -> compiler serialized the per-k
// global A-loads (waitcnt vmcnt(0) per MFMA, ~600cy each, 4 waves, 1 blk/CU).
// Fix: explicit depth-8 register ring for A-fragments; merged K-segments so
// the pipeline stays full across the x|h / h1|h2 seam.
//   - 256 blocks x 256 threads, 1 block/CU (137 KiB dynamic LDS forces it).
//   - Block b<128: layer1 units b*8..+7 (32 gate-cols, K=1536);
//     b>=128: layer2 units (b-128)*8..+7 (K=2048).
//   - Weights bf16 [col][K] in LDS, loaded ONCE. Cell state in registers.
//   - Grid barrier: arrive-counter + monotone epoch, device-scope.
// ---------------------------------------------------------------------------

typedef __bf16 bf16x8 __attribute__((ext_vector_type(8)));
typedef float f32x4 __attribute__((ext_vector_type(4)));

#define LDS_Z_OFF     131584   // Wlds: 32*(2048+8)*2 = 131584 B
#define LDS_B_OFF     140032   // Zlds: 64*33*4 = 8448 B
#define LDS_TOTAL     140160

__device__ __forceinline__ unsigned short f2bf(float f) {
  unsigned u = __float_as_uint(f);
  unsigned r = (u + 0x7FFFu + ((u >> 16) & 1u)) >> 16;  // RNE (finite inputs)
  return (unsigned short)r;
}

// in: fp32 [R][C] row-major  ->  out: bf16 [C][R] row-major (i.e. B^T layout)
__global__ __launch_bounds__(256) void transpose_to_bf16(
    const float* __restrict__ in, unsigned short* __restrict__ out, int R, int C) {
  __shared__ float tile[32][33];
  int tx = threadIdx.x & 31, ty = threadIdx.x >> 5;  // 32 x 8
  int c0 = blockIdx.x * 32, r0 = blockIdx.y * 32;
#pragma unroll
  for (int i = 0; i < 4; ++i)
    tile[ty + i * 8][tx] = in[(size_t)(r0 + ty + i * 8) * C + (c0 + tx)];
  __syncthreads();
#pragma unroll
  for (int i = 0; i < 4; ++i)
    out[(size_t)(c0 + ty + i * 8) * R + (r0 + tx)] = f2bf(tile[tx][ty + i * 8]);
}

__global__ __launch_bounds__(256) void convert_to_bf16(
    const float* __restrict__ in, unsigned short* __restrict__ out, int n4) {
  int i = blockIdx.x * 256 + threadIdx.x;
  if (i >= n4) return;
  float4 v = reinterpret_cast<const float4*>(in)[i];
  ushort4 o;
  o.x = f2bf(v.x); o.y = f2bf(v.y); o.z = f2bf(v.z); o.w = f2bf(v.w);
  reinterpret_cast<ushort4*>(out)[i] = o;
}

__global__ void init_bar(unsigned* __restrict__ bar) { bar[threadIdx.x] = 0u; }

// Grid barrier: arrive-counter + monotonically increasing epoch (unique per
// step, so no sense-reversal race). Device-scope; worked in R3.
__device__ __forceinline__ void grid_barrier(unsigned* __restrict__ arrive,
                                             unsigned* __restrict__ epoch,
                                             unsigned want) {
  __syncthreads();
  if (threadIdx.x == 0) {
    __threadfence();  // release: h stores -> device-visible
    unsigned old = __hip_atomic_fetch_add(arrive, 1u, __ATOMIC_ACQ_REL,
                                          __HIP_MEMORY_SCOPE_AGENT);
    if (old == 255u) {
      __hip_atomic_store(arrive, 0u, __ATOMIC_RELAXED, __HIP_MEMORY_SCOPE_AGENT);
      __hip_atomic_store(epoch, want, __ATOMIC_RELEASE, __HIP_MEMORY_SCOPE_AGENT);
    } else {
      while (__hip_atomic_load(epoch, __ATOMIC_ACQUIRE,
                               __HIP_MEMORY_SCOPE_AGENT) != want)
        __builtin_amdgcn_s_sleep(1);
    }
    __threadfence();  // acquire: invalidate caches before consuming new h
  }
  __syncthreads();
}

// Pipelined dual-column GEMM strip: NTOT k-steps of 32, A from global via a
// depth-8 register ring (keeps ~8 vmem in flight -> vmcnt(7) waits instead of
// vmcnt(0)), B (2 column-tiles) from LDS. Segment seam at N0 is static.
template <int N0, int NTOT>
__device__ __forceinline__ void gemm_strip(
    const unsigned short* __restrict__ a0,   // + quad*8 already
    const unsigned short* __restrict__ a1,   // + quad*8 already
    const unsigned short* __restrict__ Bp0,
    const unsigned short* __restrict__ Bp1,
    f32x4& acc0, f32x4& acc1) {
  bf16x8 abuf[8];
#pragma unroll
  for (int i = 0; i < 8 && i < NTOT; ++i)
    abuf[i] = *(const bf16x8*)(i < N0 ? a0 + i * 32 : a1 + (i - N0) * 32);
#pragma unroll
  for (int ks = 0; ks < NTOT; ++ks) {
    bf16x8 a = abuf[ks & 7];
    const int kn = ks + 8;
    if (kn < NTOT)
      abuf[ks & 7] =
          *(const bf16x8*)(kn < N0 ? a0 + kn * 32 : a1 + (kn - N0) * 32);
    bf16x8 w0 = *(const bf16x8*)(Bp0 + ks * 32);
    bf16x8 w1 = *(const bf16x8*)(Bp1 + ks * 32);
    acc0 = __builtin_amdgcn_mfma_f32_16x16x32_bf16(a, w0, acc0, 0, 0, 0);
    acc1 = __builtin_amdgcn_mfma_f32_16x16x32_bf16(a, w1, acc1, 0, 0, 0);
  }
}

__global__ __launch_bounds__(256, 1) void lstm_persistent(
    const unsigned short* __restrict__ xbf,   // [64][256][512] bf16
    const unsigned short* __restrict__ W1t,   // [4096][512]
    const unsigned short* __restrict__ U1t,   // [4096][1024]
    const float* __restrict__ b1,
    const unsigned short* __restrict__ W2t,   // [4096][1024]
    const unsigned short* __restrict__ U2t,   // [4096][1024]
    const float* __restrict__ b2,
    unsigned short* __restrict__ h1r,         // [2][64][1024] bf16
    unsigned short* __restrict__ h2r,         // [2][64][1024] bf16
    unsigned* __restrict__ bar)               // [0]=arrive, [64]=epoch
{
  extern __shared__ __align__(16) char smem[];
  const int blk = blockIdx.x;
  const bool is2 = blk >= 128;
  const int lb  = is2 ? blk - 128 : blk;
  const int u0  = lb * 8;                 // first owned unit
  const int K   = is2 ? 2048 : 1536;
  const int pitch = K + 8;
  unsigned short* Wlds = (unsigned short*)smem;          // [32][pitch]
  float* Zlds = (float*)(smem + LDS_Z_OFF);              // [64][33]
  float* Blds = (float*)(smem + LDS_B_OFF);              // [32] bias

  const int tid = threadIdx.x;

  // ---- one-time: weight slice -> LDS (row r: gate r>>3, unit u0+(r&7)) ----
  {
    const int r = tid >> 3, sub = tid & 7;               // 32 rows x 8 threads
    const int c = (r >> 3) * 1024 + u0 + (r & 7);        // global gate-col
    const unsigned short* wsrc;
    const unsigned short* usrc;
    int wk;
    if (is2) { wsrc = W2t + (size_t)c * 1024; usrc = U2t + (size_t)c * 1024; wk = 1024; }
    else     { wsrc = W1t + (size_t)c * 512;  usrc = U1t + (size_t)c * 1024; wk = 512;  }
    unsigned short* dst = Wlds + r * pitch;
    for (int k = sub * 8; k < wk; k += 64)
      *(uint4*)(dst + k) = *(const uint4*)(wsrc + k);
    for (int k = sub * 8; k < 1024; k += 64)
      *(uint4*)(dst + wk + k) = *(const uint4*)(usrc + k);
    if (tid < 32) {
      const float* bias = is2 ? b2 : b1;
      Blds[tid] = bias[(tid >> 3) * 1024 + u0 + (tid & 7)];
    }
  }
  __syncthreads();

  const int wave = tid >> 6, lane = tid & 63;
  const int quad = lane >> 4, l16 = lane & 15;
  const int m = wave * 16 + l16;                         // batch row (A)
  const unsigned short* Bp0 = Wlds + l16 * pitch + quad * 8;
  const unsigned short* Bp1 = Wlds + (16 + l16) * pitch + quad * 8;

  const int eb = tid >> 3, eu = tid & 7;
  float cLo = 0.f, cHi = 0.f;
  const float bz0 = Blds[eu], bz1 = Blds[8 + eu], bz2 = Blds[16 + eu],
              bz3 = Blds[24 + eu];

  for (int s = 0; s <= 256; ++s) {
    const int t = is2 ? (s - 1) : s;
    if (t >= 0 && t < 256) {
      f32x4 acc0 = {0.f, 0.f, 0.f, 0.f}, acc1 = {0.f, 0.f, 0.f, 0.f};
      if (!is2) {
        const unsigned short* ax =
            xbf + ((size_t)m * 256 + t) * 512 + quad * 8;
        const unsigned short* ah =
            h1r + (size_t)((t - 1) & 1) * 65536 + (size_t)m * 1024 + quad * 8;
        if (t > 0) gemm_strip<16, 48>(ax, ah, Bp0, Bp1, acc0, acc1);
        else       gemm_strip<16, 16>(ax, ax, Bp0, Bp1, acc0, acc1);
      } else {
        const unsigned short* ah1 =
            h1r + (size_t)(t & 1) * 65536 + (size_t)m * 1024 + quad * 8;
        const unsigned short* ah2 =
            h2r + (size_t)((t - 1) & 1) * 65536 + (size_t)m * 1024 + quad * 8;
        if (t > 0) gemm_strip<32, 64>(ah1, ah2, Bp0, Bp1, acc0, acc1);
        else       gemm_strip<32, 32>(ah1, ah1, Bp0, Bp1, acc0, acc1);
      }

      // exchange z across waves: C/D layout col=lane&15, row=quad*4+i
#pragma unroll
      for (int i = 0; i < 4; ++i) {
        Zlds[(wave * 16 + quad * 4 + i) * 33 + l16]      = acc0[i];
        Zlds[(wave * 16 + quad * 4 + i) * 33 + 16 + l16] = acc1[i];
      }
      __syncthreads();

      unsigned short* hring = is2 ? h2r : h1r;
      const size_t hbase = (size_t)(t & 1) * 65536 + u0 + eu;
      {
        float zi = Zlds[eb * 33 + eu]      + bz0;
        float zf = Zlds[eb * 33 + 8 + eu]  + bz1;
        float zg = Zlds[eb * 33 + 16 + eu] + bz2;
        float zo = Zlds[eb * 33 + 24 + eu] + bz3;
        float ig = 1.f / (1.f + __expf(-zi));
        float fg = 1.f / (1.f + __expf(-zf));
        float gg = 1.f - 2.f / (1.f + __expf(2.f * zg));
        float og = 1.f / (1.f + __expf(-zo));
        cLo = fg * cLo + ig * gg;
        float h = og * (1.f - 2.f / (1.f + __expf(2.f * cLo)));
        hring[hbase + (size_t)eb * 1024] = f2bf(h);
      }
      {
        int br = eb + 32;
        float zi = Zlds[br * 33 + eu]      + bz0;
        float zf = Zlds[br * 33 + 8 + eu]  + bz1;
        float zg = Zlds[br * 33 + 16 + eu] + bz2;
        float zo = Zlds[br * 33 + 24 + eu] + bz3;
        float ig = 1.f / (1.f + __expf(-zi));
        float fg = 1.f / (1.f + __expf(-zf));
        float gg = 1.f - 2.f / (1.f + __expf(2.f * zg));
        float og = 1.f / (1.f + __expf(-zo));
        cHi = fg * cHi + ig * gg;
        float h = og * (1.f - 2.f / (1.f + __expf(2.f * cHi)));
        hring[hbase + (size_t)br * 1024] = f2bf(h);
      }
    }
    if (s < 256) grid_barrier(&bar[0], &bar[64], (unsigned)(s + 1));
  }
}

// out[64][512] = h2_last @ Wd + bd.  One wave per 16x16 tile, K=1024.
__global__ __launch_bounds__(64) void dense_kernel(
    const unsigned short* __restrict__ h2,   // [64][1024] bf16
    const unsigned short* __restrict__ Wdt,  // [512][1024] bf16
    const float* __restrict__ bd,
    float* __restrict__ out) {
  int mt = blockIdx.x >> 5;  // 0..3
  int nt = blockIdx.x & 31;  // 0..31
  int lane = threadIdx.x;
  int quad = lane >> 4, l16 = lane & 15;
  f32x4 acc = {0.f, 0.f, 0.f, 0.f};
  const unsigned short* ap = h2 + (size_t)(mt * 16 + l16) * 1024 + quad * 8;
  const unsigned short* bp = Wdt + (size_t)(nt * 16 + l16) * 1024 + quad * 8;
#pragma unroll
  for (int ks = 0; ks < 32; ++ks) {
    bf16x8 a = *reinterpret_cast<const bf16x8*>(ap + ks * 32);
    bf16x8 b = *reinterpret_cast<const bf16x8*>(bp + ks * 32);
    acc = __builtin_amdgcn_mfma_f32_16x16x32_bf16(a, b, acc, 0, 0, 0);
  }
  int colo = nt * 16 + l16;
  float bias = bd[colo];
#pragma unroll
  for (int i = 0; i < 4; ++i)
    out[(size_t)(mt * 16 + quad * 4 + i) * 512 + colo] = acc[i] + bias;
}

extern "C" void kernel_launch(void* const* d_in, const int* in_sizes, int n_in,
                              void* d_out, int out_size, void* d_ws, size_t ws_size,
                              hipStream_t stream) {
  const float* x  = (const float*)d_in[0];
  const float* W1 = (const float*)d_in[1];
  const float* U1 = (const float*)d_in[2];
  const float* b1 = (const float*)d_in[3];
  const float* W2 = (const float*)d_in[4];
  const float* U2 = (const float*)d_in[5];
  const float* b2 = (const float*)d_in[6];
  const float* Wd = (const float*)d_in[7];
  const float* bd = (const float*)d_in[8];
  float* out = (float*)d_out;

  char* p = (char*)d_ws;
  auto carve = [&](size_t bytes) -> char* {
    char* r = p;
    p += (bytes + 255) & ~(size_t)255;
    return r;
  };
  // ~45.5 MiB total (R2-proven budget; R1's 78 MiB overflowed ws)
  unsigned short* W1t = (unsigned short*)carve((size_t)4096 * 512 * 2);
  unsigned short* U1t = (unsigned short*)carve((size_t)4096 * 1024 * 2);
  unsigned short* W2t = (unsigned short*)carve((size_t)4096 * 1024 * 2);
  unsigned short* U2t = (unsigned short*)carve((size_t)4096 * 1024 * 2);
  unsigned short* Wdt = (unsigned short*)carve((size_t)512 * 1024 * 2);
  unsigned short* xbf = (unsigned short*)carve((size_t)64 * 256 * 512 * 2);
  unsigned short* h1r = (unsigned short*)carve((size_t)2 * 64 * 1024 * 2);
  unsigned short* h2r = (unsigned short*)carve((size_t)2 * 64 * 1024 * 2);
  unsigned* bar = (unsigned*)carve(256 * 4);
  (void)ws_size; (void)in_sizes; (void)n_in; (void)out_size;

  transpose_to_bf16<<<dim3(128, 16), 256, 0, stream>>>(W1, W1t, 512, 4096);
  transpose_to_bf16<<<dim3(128, 32), 256, 0, stream>>>(U1, U1t, 1024, 4096);
  transpose_to_bf16<<<dim3(128, 32), 256, 0, stream>>>(W2, W2t, 1024, 4096);
  transpose_to_bf16<<<dim3(128, 32), 256, 0, stream>>>(U2, U2t, 1024, 4096);
  transpose_to_bf16<<<dim3(16, 32), 256, 0, stream>>>(Wd, Wdt, 1024, 512);
  convert_to_bf16<<<8192, 256, 0, stream>>>(x, xbf, 64 * 256 * 512 / 4);
  init_bar<<<1, 256, 0, stream>>>(bar);

  hipFuncSetAttribute(reinterpret_cast<const void*>(lstm_persistent),
                      hipFuncAttributeMaxDynamicSharedMemorySize, LDS_TOTAL);
  lstm_persistent<<<256, 256, LDS_TOTAL, stream>>>(
      xbf, W1t, U1t, b1, W2t, U2t, b2, h1r, h2r, bar);

  dense_kernel<<<128, 64, 0, stream>>>(h2r + 65536, Wdt, bd, out);
}

// Round 5
// 2674.317 us; speedup vs baseline: 4.1880x; 4.1880x over previous
//
#include <hip/hip_runtime.h>

// ---------------------------------------------------------------------------
// 2-layer LSTM (B=64, T=256, D=512, H1=H2=1024) + dense head.
// R5: fence-free persistent kernel.
// R3/R4 post-mortem: compute-loop changes had ZERO effect (43us/step both) ->
// bottleneck is the grid barrier: __threadfence (agent release/acquire) emits
// buffer_wbl2/buffer_inv L2 maintenance per block per step (~64 L2 ops/XCD),
// plus 256 serialized ACQ_REL RMWs on one line. Fix:
//   - h/x data ops use sc1 (device scope, MALL-coherent) inline-asm loads and
//     stores -> NO fences needed anywhere. vmcnt(0) drain before arrival.
//   - tree barrier: 8 group counters + root + 8 epoch lines, all RELAXED
//     agent atomics, monotone (no resets).
//   - A-loads hand-pipelined: 16-deep ring, manual s_waitcnt vmcnt(N)
//     (template recursion for constant immediates, "+v"-chained waits).
// Weights bf16 [col][K] in LDS (loaded once); cell state in registers.
// ---------------------------------------------------------------------------

typedef __bf16 bf16x8 __attribute__((ext_vector_type(8)));
typedef float f32x4 __attribute__((ext_vector_type(4)));
typedef unsigned int u32x4 __attribute__((ext_vector_type(4)));

#define LDS_Z_OFF     131584   // Wlds: 32*(2048+8)*2 = 131584 B
#define LDS_B_OFF     140032   // Zlds: 64*33*4 = 8448 B
#define LDS_TOTAL     140160

__device__ __forceinline__ unsigned short f2bf(float f) {
  unsigned u = __float_as_uint(f);
  unsigned r = (u + 0x7FFFu + ((u >> 16) & 1u)) >> 16;  // RNE (finite inputs)
  return (unsigned short)r;
}

// in: fp32 [R][C] row-major  ->  out: bf16 [C][R] row-major (i.e. B^T layout)
__global__ __launch_bounds__(256) void transpose_to_bf16(
    const float* __restrict__ in, unsigned short* __restrict__ out, int R, int C) {
  __shared__ float tile[32][33];
  int tx = threadIdx.x & 31, ty = threadIdx.x >> 5;  // 32 x 8
  int c0 = blockIdx.x * 32, r0 = blockIdx.y * 32;
#pragma unroll
  for (int i = 0; i < 4; ++i)
    tile[ty + i * 8][tx] = in[(size_t)(r0 + ty + i * 8) * C + (c0 + tx)];
  __syncthreads();
#pragma unroll
  for (int i = 0; i < 4; ++i)
    out[(size_t)(c0 + ty + i * 8) * R + (r0 + tx)] = f2bf(tile[tx][ty + i * 8]);
}

__global__ __launch_bounds__(256) void convert_to_bf16(
    const float* __restrict__ in, unsigned short* __restrict__ out, int n4) {
  int i = blockIdx.x * 256 + threadIdx.x;
  if (i >= n4) return;
  float4 v = reinterpret_cast<const float4*>(in)[i];
  ushort4 o;
  o.x = f2bf(v.x); o.y = f2bf(v.y); o.z = f2bf(v.z); o.w = f2bf(v.w);
  reinterpret_cast<ushort4*>(out)[i] = o;
}

__global__ void init_bar(unsigned* __restrict__ bar) { bar[threadIdx.x] = 0u; }

// ---- manual-pipelined A-load machinery (sc1 = device scope, MALL) ---------
template <int I, int NPRE, int N0, int DEPTH>
__device__ __forceinline__ void strip_pre(u32x4 (&abuf)[DEPTH],
    const unsigned short* a0, const unsigned short* a1) {
  if constexpr (I < NPRE) {
    constexpr int OFF = (I < N0) ? I * 64 : (I - N0) * 64;
    if constexpr (I < N0)
      asm volatile("global_load_dwordx4 %0, %1, off offset:%2 sc1"
                   : "=v"(abuf[I % DEPTH]) : "v"(a0), "i"(OFF));
    else
      asm volatile("global_load_dwordx4 %0, %1, off offset:%2 sc1"
                   : "=v"(abuf[I % DEPTH]) : "v"(a1), "i"(OFF));
    strip_pre<I + 1, NPRE, N0, DEPTH>(abuf, a0, a1);
  }
}

template <int KS, int N0, int NTOT, int DEPTH>
__device__ __forceinline__ void strip_iter(u32x4 (&abuf)[DEPTH],
    const unsigned short* a0, const unsigned short* a1,
    const unsigned short* Bp0, const unsigned short* Bp1,
    f32x4& acc0, f32x4& acc1) {
  if constexpr (KS < NTOT) {
    // loads issued so far: min(KS + DEPTH, NTOT); need load KS complete
    constexpr int ISSUED = (KS + DEPTH < NTOT) ? (KS + DEPTH) : NTOT;
    constexpr int WAIT = ISSUED - KS - 1;   // DEPTH-1 steady, tapering tail
    asm volatile("s_waitcnt vmcnt(%1)"
                 : "+v"(abuf[KS % DEPTH]) : "i"(WAIT));
    bf16x8 a = __builtin_bit_cast(bf16x8, abuf[KS % DEPTH]);
    constexpr int KN = KS + DEPTH;          // refill freed slot
    if constexpr (KN < NTOT) {
      constexpr int OFF = (KN < N0) ? KN * 64 : (KN - N0) * 64;
      if constexpr (KN < N0)
        asm volatile("global_load_dwordx4 %0, %1, off offset:%2 sc1"
                     : "=v"(abuf[KN % DEPTH]) : "v"(a0), "i"(OFF));
      else
        asm volatile("global_load_dwordx4 %0, %1, off offset:%2 sc1"
                     : "=v"(abuf[KN % DEPTH]) : "v"(a1), "i"(OFF));
    }
    bf16x8 w0 = *(const bf16x8*)(Bp0 + KS * 32);
    bf16x8 w1 = *(const bf16x8*)(Bp1 + KS * 32);
    acc0 = __builtin_amdgcn_mfma_f32_16x16x32_bf16(a, w0, acc0, 0, 0, 0);
    acc1 = __builtin_amdgcn_mfma_f32_16x16x32_bf16(a, w1, acc1, 0, 0, 0);
    strip_iter<KS + 1, N0, NTOT, DEPTH>(abuf, a0, a1, Bp0, Bp1, acc0, acc1);
  }
}

template <int N0, int NTOT>
__device__ __forceinline__ void gemm_strip(
    const unsigned short* a0, const unsigned short* a1,
    const unsigned short* Bp0, const unsigned short* Bp1,
    f32x4& acc0, f32x4& acc1) {
  constexpr int DEPTH = 16;
  u32x4 abuf[DEPTH];
  strip_pre<0, (NTOT < DEPTH ? NTOT : DEPTH), N0, DEPTH>(abuf, a0, a1);
  strip_iter<0, N0, NTOT, DEPTH>(abuf, a0, a1, Bp0, Bp1, acc0, acc1);
}

__device__ __forceinline__ void store_h_sc1(unsigned short* p, unsigned v) {
  asm volatile("global_store_short %0, %1, off sc1" :: "v"(p), "v"(v) : "memory");
}

// Fence-free tree barrier. bar lines (128B apart): [0]=root,
// [32*(1+g)]=group ctr, [32*(9+g)]=epoch copy. Monotone counters, no resets.
// Precondition: callers' h stores are sc1 (MALL-coherent) and drained here.
__device__ __forceinline__ void grid_barrier(unsigned* __restrict__ bar,
                                             int g, unsigned want) {
  asm volatile("s_waitcnt vmcnt(0)" ::: "memory");  // every thread: h stores acked
  __syncthreads();
  if (threadIdx.x == 0) {
    unsigned old = __hip_atomic_fetch_add(bar + 32 * (1 + g), 1u,
                                          __ATOMIC_RELAXED, __HIP_MEMORY_SCOPE_AGENT);
    if (old == 32u * want - 1u) {               // last of group
      unsigned r = __hip_atomic_fetch_add(bar, 1u, __ATOMIC_RELAXED,
                                          __HIP_MEMORY_SCOPE_AGENT);
      if (r == 8u * want - 1u) {                // last group -> publish epoch
#pragma unroll
        for (int i = 0; i < 8; ++i)
          __hip_atomic_store(bar + 32 * (9 + i), want, __ATOMIC_RELAXED,
                             __HIP_MEMORY_SCOPE_AGENT);
      }
    }
    while (__hip_atomic_load(bar + 32 * (9 + g), __ATOMIC_RELAXED,
                             __HIP_MEMORY_SCOPE_AGENT) < want)
      __builtin_amdgcn_s_sleep(1);
  }
  __syncthreads();
}

__global__ __launch_bounds__(256, 1) void lstm_persistent(
    const unsigned short* __restrict__ xbf,   // [64][256][512] bf16
    const unsigned short* __restrict__ W1t,   // [4096][512]
    const unsigned short* __restrict__ U1t,   // [4096][1024]
    const float* __restrict__ b1,
    const unsigned short* __restrict__ W2t,   // [4096][1024]
    const unsigned short* __restrict__ U2t,   // [4096][1024]
    const float* __restrict__ b2,
    unsigned short* __restrict__ h1r,         // [2][64][1024] bf16
    unsigned short* __restrict__ h2r,         // [2][64][1024] bf16
    unsigned* __restrict__ bar)
{
  extern __shared__ __align__(16) char smem[];
  const int blk = blockIdx.x;
  const bool is2 = blk >= 128;
  const int lb  = is2 ? blk - 128 : blk;
  const int u0  = lb * 8;                 // first owned unit
  const int K   = is2 ? 2048 : 1536;
  const int pitch = K + 8;
  unsigned short* Wlds = (unsigned short*)smem;          // [32][pitch]
  float* Zlds = (float*)(smem + LDS_Z_OFF);              // [64][33]
  float* Blds = (float*)(smem + LDS_B_OFF);              // [32] bias
  const int g = blk & 7;                  // probable XCD (round-robin); any
                                          // mapping is correct, this is locality
  const int tid = threadIdx.x;

  // ---- one-time: weight slice -> LDS (row r: gate r>>3, unit u0+(r&7)) ----
  {
    const int r = tid >> 3, sub = tid & 7;               // 32 rows x 8 threads
    const int c = (r >> 3) * 1024 + u0 + (r & 7);        // global gate-col
    const unsigned short* wsrc;
    const unsigned short* usrc;
    int wk;
    if (is2) { wsrc = W2t + (size_t)c * 1024; usrc = U2t + (size_t)c * 1024; wk = 1024; }
    else     { wsrc = W1t + (size_t)c * 512;  usrc = U1t + (size_t)c * 1024; wk = 512;  }
    unsigned short* dst = Wlds + r * pitch;
    for (int k = sub * 8; k < wk; k += 64)
      *(uint4*)(dst + k) = *(const uint4*)(wsrc + k);
    for (int k = sub * 8; k < 1024; k += 64)
      *(uint4*)(dst + wk + k) = *(const uint4*)(usrc + k);
    if (tid < 32) {
      const float* bias = is2 ? b2 : b1;
      Blds[tid] = bias[(tid >> 3) * 1024 + u0 + (tid & 7)];
    }
  }
  __syncthreads();

  const int wave = tid >> 6, lane = tid & 63;
  const int quad = lane >> 4, l16 = lane & 15;
  const int m = wave * 16 + l16;                         // batch row (A)
  const unsigned short* Bp0 = Wlds + l16 * pitch + quad * 8;
  const unsigned short* Bp1 = Wlds + (16 + l16) * pitch + quad * 8;

  const int eb = tid >> 3, eu = tid & 7;
  float cLo = 0.f, cHi = 0.f;
  const float bz0 = Blds[eu], bz1 = Blds[8 + eu], bz2 = Blds[16 + eu],
              bz3 = Blds[24 + eu];

  for (int s = 0; s <= 256; ++s) {
    const int t = is2 ? (s - 1) : s;
    if (t >= 0 && t < 256) {
      f32x4 acc0 = {0.f, 0.f, 0.f, 0.f}, acc1 = {0.f, 0.f, 0.f, 0.f};
      if (!is2) {
        const unsigned short* ax =
            xbf + ((size_t)m * 256 + t) * 512 + quad * 8;
        const unsigned short* ah =
            h1r + (size_t)((t - 1) & 1) * 65536 + (size_t)m * 1024 + quad * 8;
        if (t > 0) gemm_strip<16, 48>(ax, ah, Bp0, Bp1, acc0, acc1);
        else       gemm_strip<16, 16>(ax, ax, Bp0, Bp1, acc0, acc1);
      } else {
        const unsigned short* ah1 =
            h1r + (size_t)(t & 1) * 65536 + (size_t)m * 1024 + quad * 8;
        const unsigned short* ah2 =
            h2r + (size_t)((t - 1) & 1) * 65536 + (size_t)m * 1024 + quad * 8;
        if (t > 0) gemm_strip<32, 64>(ah1, ah2, Bp0, Bp1, acc0, acc1);
        else       gemm_strip<32, 32>(ah1, ah1, Bp0, Bp1, acc0, acc1);
      }

      // exchange z across waves: C/D layout col=lane&15, row=quad*4+i
#pragma unroll
      for (int i = 0; i < 4; ++i) {
        Zlds[(wave * 16 + quad * 4 + i) * 33 + l16]      = acc0[i];
        Zlds[(wave * 16 + quad * 4 + i) * 33 + 16 + l16] = acc1[i];
      }
      __syncthreads();

      unsigned short* hring = is2 ? h2r : h1r;
      unsigned short* hp = hring + (size_t)(t & 1) * 65536 + u0 + eu;
      {
        float zi = Zlds[eb * 33 + eu]      + bz0;
        float zf = Zlds[eb * 33 + 8 + eu]  + bz1;
        float zg = Zlds[eb * 33 + 16 + eu] + bz2;
        float zo = Zlds[eb * 33 + 24 + eu] + bz3;
        float ig = 1.f / (1.f + __expf(-zi));
        float fg = 1.f / (1.f + __expf(-zf));
        float gg = 1.f - 2.f / (1.f + __expf(2.f * zg));
        float og = 1.f / (1.f + __expf(-zo));
        cLo = fg * cLo + ig * gg;
        float h = og * (1.f - 2.f / (1.f + __expf(2.f * cLo)));
        store_h_sc1(hp + (size_t)eb * 1024, (unsigned)f2bf(h));
      }
      {
        int br = eb + 32;
        float zi = Zlds[br * 33 + eu]      + bz0;
        float zf = Zlds[br * 33 + 8 + eu]  + bz1;
        float zg = Zlds[br * 33 + 16 + eu] + bz2;
        float zo = Zlds[br * 33 + 24 + eu] + bz3;
        float ig = 1.f / (1.f + __expf(-zi));
        float fg = 1.f / (1.f + __expf(-zf));
        float gg = 1.f - 2.f / (1.f + __expf(2.f * zg));
        float og = 1.f / (1.f + __expf(-zo));
        cHi = fg * cHi + ig * gg;
        float h = og * (1.f - 2.f / (1.f + __expf(2.f * cHi)));
        store_h_sc1(hp + (size_t)br * 1024, (unsigned)f2bf(h));
      }
    }
    if (s < 256) grid_barrier(bar, g, (unsigned)(s + 1));
  }
}

// out[64][512] = h2_last @ Wd + bd.  One wave per 16x16 tile, K=1024.
// (kernel boundary = implicit device-wide release; normal cached loads OK)
__global__ __launch_bounds__(64) void dense_kernel(
    const unsigned short* __restrict__ h2,   // [64][1024] bf16
    const unsigned short* __restrict__ Wdt,  // [512][1024] bf16
    const float* __restrict__ bd,
    float* __restrict__ out) {
  int mt = blockIdx.x >> 5;  // 0..3
  int nt = blockIdx.x & 31;  // 0..31
  int lane = threadIdx.x;
  int quad = lane >> 4, l16 = lane & 15;
  f32x4 acc = {0.f, 0.f, 0.f, 0.f};
  const unsigned short* ap = h2 + (size_t)(mt * 16 + l16) * 1024 + quad * 8;
  const unsigned short* bp = Wdt + (size_t)(nt * 16 + l16) * 1024 + quad * 8;
#pragma unroll
  for (int ks = 0; ks < 32; ++ks) {
    bf16x8 a = *reinterpret_cast<const bf16x8*>(ap + ks * 32);
    bf16x8 b = *reinterpret_cast<const bf16x8*>(bp + ks * 32);
    acc = __builtin_amdgcn_mfma_f32_16x16x32_bf16(a, b, acc, 0, 0, 0);
  }
  int colo = nt * 16 + l16;
  float bias = bd[colo];
#pragma unroll
  for (int i = 0; i < 4; ++i)
    out[(size_t)(mt * 16 + quad * 4 + i) * 512 + colo] = acc[i] + bias;
}

extern "C" void kernel_launch(void* const* d_in, const int* in_sizes, int n_in,
                              void* d_out, int out_size, void* d_ws, size_t ws_size,
                              hipStream_t stream) {
  const float* x  = (const float*)d_in[0];
  const float* W1 = (const float*)d_in[1];
  const float* U1 = (const float*)d_in[2];
  const float* b1 = (const float*)d_in[3];
  const float* W2 = (const float*)d_in[4];
  const float* U2 = (const float*)d_in[5];
  const float* b2 = (const float*)d_in[6];
  const float* Wd = (const float*)d_in[7];
  const float* bd = (const float*)d_in[8];
  float* out = (float*)d_out;

  char* p = (char*)d_ws;
  auto carve = [&](size_t bytes) -> char* {
    char* r = p;
    p += (bytes + 255) & ~(size_t)255;
    return r;
  };
  // ~45.5 MiB total (R2-proven budget; R1's 78 MiB overflowed ws)
  unsigned short* W1t = (unsigned short*)carve((size_t)4096 * 512 * 2);
  unsigned short* U1t = (unsigned short*)carve((size_t)4096 * 1024 * 2);
  unsigned short* W2t = (unsigned short*)carve((size_t)4096 * 1024 * 2);
  unsigned short* U2t = (unsigned short*)carve((size_t)4096 * 1024 * 2);
  unsigned short* Wdt = (unsigned short*)carve((size_t)512 * 1024 * 2);
  unsigned short* xbf = (unsigned short*)carve((size_t)64 * 256 * 512 * 2);
  unsigned short* h1r = (unsigned short*)carve((size_t)2 * 64 * 1024 * 2);
  unsigned short* h2r = (unsigned short*)carve((size_t)2 * 64 * 1024 * 2);
  unsigned* bar = (unsigned*)carve(1024 * 4);
  (void)ws_size; (void)in_sizes; (void)n_in; (void)out_size;

  transpose_to_bf16<<<dim3(128, 16), 256, 0, stream>>>(W1, W1t, 512, 4096);
  transpose_to_bf16<<<dim3(128, 32), 256, 0, stream>>>(U1, U1t, 1024, 4096);
  transpose_to_bf16<<<dim3(128, 32), 256, 0, stream>>>(W2, W2t, 1024, 4096);
  transpose_to_bf16<<<dim3(128, 32), 256, 0, stream>>>(U2, U2t, 1024, 4096);
  transpose_to_bf16<<<dim3(16, 32), 256, 0, stream>>>(Wd, Wdt, 1024, 512);
  convert_to_bf16<<<8192, 256, 0, stream>>>(x, xbf, 64 * 256 * 512 / 4);
  init_bar<<<1, 1024, 0, stream>>>(bar);

  hipFuncSetAttribute(reinterpret_cast<const void*>(lstm_persistent),
                      hipFuncAttributeMaxDynamicSharedMemorySize, LDS_TOTAL);
  lstm_persistent<<<256, 256, LDS_TOTAL, stream>>>(
      xbf, W1t, U1t, b1, W2t, U2t, b2, h1r, h2r, bar);

  dense_kernel<<<128, 64, 0, stream>>>(h2r + 65536, Wdt, bd, out);
}